// Round 1
// 326.215 us; speedup vs baseline: 1.0107x; 1.0107x over previous
//
#include <hip/hip_runtime.h>
#include <hip/hip_bf16.h>

typedef __bf16 bf16x8 __attribute__((ext_vector_type(8)));
typedef float  f32x4  __attribute__((ext_vector_type(4)));
typedef float  f32x16 __attribute__((ext_vector_type(16)));
typedef unsigned int u32x2 __attribute__((ext_vector_type(2)));

#define B_   2
#define T_   2048
#define D_   2048
#define QH_  16
#define KVH_ 4
#define HD_  128
#define BT_  (B_ * T_)
#define KVD_ 512
#define SCL  0.12751744f   // log2(e)/sqrt(128); folded into wq during cvt

// async global->LDS, 16B/lane; LDS dest = wave-uniform base + lane*16
#define GLOAD_LDS16(g, l)                                        \
  __builtin_amdgcn_global_load_lds(                              \
      (const __attribute__((address_space(1))) void*)(g),        \
      (__attribute__((address_space(3))) void*)(l), 16, 0, 0)

// ---------------------------------------------------------------------------
// Fused fp32->bf16 conversion for all five inputs -> [xb|wqb|wkb|wvb|wob].
// wq pre-scaled by SCL so QK^T scores come out in exp2 domain.
// ---------------------------------------------------------------------------
__global__ __launch_bounds__(256) void cvt_all(
    const float* __restrict__ x, const float* __restrict__ wq,
    const float* __restrict__ wk, const float* __restrict__ wv,
    const float* __restrict__ wo, ushort* __restrict__ out) {
  const int i = blockIdx.x * 256 + threadIdx.x;  // float4 idx; 4718592 total
  int j = i;
  const float* src;
  float mul = 1.f;
  if (j < 2097152) { src = x; }
  else if ((j -= 2097152) < 1048576) { src = wq; mul = SCL; }
  else if ((j -= 1048576) < 262144)  { src = wk; }
  else if ((j -= 262144) < 262144)   { src = wv; }
  else { j -= 262144; src = wo; }
  float4 v = ((const float4*)src)[j];
  __hip_bfloat16 h0 = __float2bfloat16(v.x * mul);
  __hip_bfloat16 h1 = __float2bfloat16(v.y * mul);
  __hip_bfloat16 h2 = __float2bfloat16(v.z * mul);
  __hip_bfloat16 h3 = __float2bfloat16(v.w * mul);
  ushort4 o;
  o.x = *(ushort*)&h0; o.y = *(ushort*)&h1;
  o.z = *(ushort*)&h2; o.w = *(ushort*)&h3;
  ((ushort4*)out)[i] = o;
}

// ---------------------------------------------------------------------------
// Fused QKV projection, 128x128 tile, BK=64 (half the barriers of BK=32),
// XOR-swizzled LDS chunks (uniform bank spread at 128B row stride).
// ---------------------------------------------------------------------------
__global__ __launch_bounds__(256) void gemm_qkv(
    const ushort* __restrict__ X, const ushort* __restrict__ WQ,
    const ushort* __restrict__ WK, const ushort* __restrict__ WV,
    ushort* __restrict__ qo, ushort* __restrict__ ko, ushort* __restrict__ vo) {
  const int nb = blockIdx.x % 24;
  const int mb = blockIdx.x / 24;
  const int tid = threadIdx.x;
  const int wave = tid >> 6;
  const int lane = tid & 63;
  const int mrow = lane & 15;
  const int quad = lane >> 4;
  const int wm = wave >> 1;
  const int wn = wave & 1;
  const int m0 = mb * 128;
  const int K = D_;

  const ushort* Wg;
  if (nb < 16)      Wg = WQ + (size_t)nb * 128 * K;
  else if (nb < 20) Wg = WK + (size_t)(nb - 16) * 128 * K;
  else              Wg = WV + (size_t)(nb - 20) * 128 * K;

  __shared__ __align__(16) ushort At[128 * 64];  // 16 KB, 8 chunks/row swizzled
  __shared__ __align__(16) ushort Bt[128 * 64];  // 16 KB

  f32x4 acc[4][4];
#pragma unroll
  for (int i = 0; i < 4; ++i)
#pragma unroll
    for (int j = 0; j < 4; ++j) acc[i][j] = (f32x4){0.f, 0.f, 0.f, 0.f};

  const ushort* Xg = X + (size_t)m0 * K;

  for (int k0 = 0; k0 < K; k0 += 64) {
#pragma unroll
    for (int p = 0; p < 4; ++p) {
      const int c = p * 256 + tid;
      const int row = c >> 3;
      const int cc = (c & 7) ^ (row & 7);
      GLOAD_LDS16(Xg + (size_t)row * K + k0 + cc * 8,
                  At + (size_t)(p * 256 + wave * 64) * 8);
      GLOAD_LDS16(Wg + (size_t)row * K + k0 + cc * 8,
                  Bt + (size_t)(p * 256 + wave * 64) * 8);
    }
    __syncthreads();

#pragma unroll
    for (int s = 0; s < 2; ++s) {
      bf16x8 af[4], bfr[4];
#pragma unroll
      for (int mt = 0; mt < 4; ++mt) {
        const int row = wm * 64 + mt * 16 + mrow;
        af[mt] = *reinterpret_cast<const bf16x8*>(
            At + row * 64 + (((s * 4 + quad) ^ (row & 7)) * 8));
      }
#pragma unroll
      for (int nt = 0; nt < 4; ++nt) {
        const int row = wn * 64 + nt * 16 + mrow;
        bfr[nt] = *reinterpret_cast<const bf16x8*>(
            Bt + row * 64 + (((s * 4 + quad) ^ (row & 7)) * 8));
      }
#pragma unroll
      for (int mt = 0; mt < 4; ++mt)
#pragma unroll
        for (int nt = 0; nt < 4; ++nt)
          acc[mt][nt] = __builtin_amdgcn_mfma_f32_16x16x32_bf16(
              af[mt], bfr[nt], acc[mt][nt], 0, 0, 0);
    }
    __syncthreads();
  }

#pragma unroll
  for (int mt = 0; mt < 4; ++mt) {
#pragma unroll
    for (int nt = 0; nt < 4; ++nt) {
      const int colw = wn * 64 + nt * 16 + mrow;
      const int row0 = m0 + wm * 64 + mt * 16 + quad * 4;
      if (nb < 16) {
        const int col = nb * 128 + colw;
#pragma unroll
        for (int r = 0; r < 4; ++r) {
          __hip_bfloat16 hh = __float2bfloat16(acc[mt][nt][r]);
          qo[(size_t)(row0 + r) * 2048 + col] = *(ushort*)&hh;
        }
      } else if (nb < 20) {
        const int col = (nb - 16) * 128 + colw;
#pragma unroll
        for (int r = 0; r < 4; ++r) {
          __hip_bfloat16 hh = __float2bfloat16(acc[mt][nt][r]);
          ko[(size_t)(row0 + r) * KVD_ + col] = *(ushort*)&hh;
        }
      } else {
        const int col = (nb - 20) * 128 + colw;
        const int bb = row0 >> 11;
        const int t0 = row0 & (T_ - 1);
        ushort4 s4;
#pragma unroll
        for (int r = 0; r < 4; ++r) {
          __hip_bfloat16 hh = __float2bfloat16(acc[mt][nt][r]);
          (&s4.x)[r] = *(ushort*)&hh;
        }
        *(ushort4*)(vo + ((size_t)(bb * KVD_ + col)) * T_ + t0) = s4;
      }
    }
  }
}

// ---------------------------------------------------------------------------
// O-projection GEMM (fp32 out), BK=64 + swizzle.
// ---------------------------------------------------------------------------
__global__ __launch_bounds__(256) void gemm_o(
    const ushort* __restrict__ X, const ushort* __restrict__ W,
    float* __restrict__ Y, int M, int N, int K) {
  const int nb128 = N >> 7;
  const int mb = blockIdx.x / nb128;
  const int nb = blockIdx.x % nb128;
  const int tid = threadIdx.x;
  const int wave = tid >> 6;
  const int lane = tid & 63;
  const int mrow = lane & 15;
  const int quad = lane >> 4;
  const int wm = wave >> 1;
  const int wn = wave & 1;
  const int m0 = mb * 128;
  const int n0 = nb * 128;

  __shared__ __align__(16) ushort At[128 * 64];
  __shared__ __align__(16) ushort Bt[128 * 64];

  f32x4 acc[4][4];
#pragma unroll
  for (int i = 0; i < 4; ++i)
#pragma unroll
    for (int j = 0; j < 4; ++j) acc[i][j] = (f32x4){0.f, 0.f, 0.f, 0.f};

  const ushort* Xg = X + (size_t)m0 * K;
  const ushort* Wg = W + (size_t)n0 * K;

  for (int k0 = 0; k0 < K; k0 += 64) {
#pragma unroll
    for (int p = 0; p < 4; ++p) {
      const int c = p * 256 + tid;
      const int row = c >> 3;
      const int cc = (c & 7) ^ (row & 7);
      GLOAD_LDS16(Xg + (size_t)row * K + k0 + cc * 8,
                  At + (size_t)(p * 256 + wave * 64) * 8);
      GLOAD_LDS16(Wg + (size_t)row * K + k0 + cc * 8,
                  Bt + (size_t)(p * 256 + wave * 64) * 8);
    }
    __syncthreads();

#pragma unroll
    for (int s = 0; s < 2; ++s) {
      bf16x8 af[4], bfr[4];
#pragma unroll
      for (int mt = 0; mt < 4; ++mt) {
        const int row = wm * 64 + mt * 16 + mrow;
        af[mt] = *reinterpret_cast<const bf16x8*>(
            At + row * 64 + (((s * 4 + quad) ^ (row & 7)) * 8));
      }
#pragma unroll
      for (int nt = 0; nt < 4; ++nt) {
        const int row = wn * 64 + nt * 16 + mrow;
        bfr[nt] = *reinterpret_cast<const bf16x8*>(
            Bt + row * 64 + (((s * 4 + quad) ^ (row & 7)) * 8));
      }
#pragma unroll
      for (int mt = 0; mt < 4; ++mt)
#pragma unroll
        for (int nt = 0; nt < 4; ++nt)
          acc[mt][nt] = __builtin_amdgcn_mfma_f32_16x16x32_bf16(
              af[mt], bfr[nt], acc[mt][nt], 0, 0, 0);
    }
    __syncthreads();
  }

#pragma unroll
  for (int mt = 0; mt < 4; ++mt)
#pragma unroll
    for (int nt = 0; nt < 4; ++nt) {
      const int col = n0 + wn * 64 + nt * 16 + mrow;
      const int row0 = m0 + wm * 64 + mt * 16 + quad * 4;
#pragma unroll
      for (int r = 0; r < 4; ++r)
        Y[(size_t)(row0 + r) * N + col] = acc[mt][nt][r];
    }
}

// ---------------------------------------------------------------------------
// RoPE in place on bf16 q [BT,16,128] (pre-scaled; rotation commutes) and k.
// ---------------------------------------------------------------------------
__global__ __launch_bounds__(256) void rope_kernel(
    __hip_bfloat16* __restrict__ q, __hip_bfloat16* __restrict__ k,
    const int* __restrict__ positions) {
  const int wave = threadIdx.x >> 6;
  const int lane = threadIdx.x & 63;
  const int p = blockIdx.x * 4 + wave;
  const int head = p % (QH_ + KVH_);
  const int bt = p / (QH_ + KVH_);

  __hip_bfloat16* base;
  if (head < QH_) base = q + ((size_t)bt * QH_ + head) * HD_;
  else            base = k + ((size_t)bt * KVH_ + (head - QH_)) * HD_;

  const float pos = (float)positions[bt];
  const float inv_freq = exp2f((float)lane * -0.20762050593f);  // -log2(1e4)/64
  const float ang = pos * inv_freq;
  const float c = cosf(ang);
  const float s = sinf(ang);

  const float x1 = __bfloat162float(base[lane]);
  const float x2 = __bfloat162float(base[lane + 64]);
  base[lane]      = __float2bfloat16(x1 * c - x2 * s);
  base[lane + 64] = __float2bfloat16(x1 * s + x2 * c);
}

// ---------------------------------------------------------------------------
// pack 2 f32 -> 1 u32 of 2 bf16 (compiler fuses to v_cvt_pk_bf16_f32)
// ---------------------------------------------------------------------------
static __device__ __forceinline__ unsigned pk2(float a, float b) {
  __hip_bfloat16 ha = __float2bfloat16(a);
  __hip_bfloat16 hb = __float2bfloat16(b);
  return (unsigned)(*(ushort*)&ha) | ((unsigned)(*(ushort*)&hb) << 16);
}

// exchange upper-32-lanes of a with lower-32-lanes of b
static __device__ __forceinline__ void hswap(unsigned& a, unsigned& b,
                                             const int hi) {
#if __has_builtin(__builtin_amdgcn_permlane32_swap)
  u32x2 r = __builtin_amdgcn_permlane32_swap(a, b, false, false);
  a = r.x;
  b = r.y;
#else
  unsigned s = __shfl_xor(hi ? a : b, 32, 64);
  unsigned na = hi ? s : a;
  b = hi ? b : s;
  a = na;
#endif
}

// ---------------------------------------------------------------------------
// Flash MFMA attention v5: swapped-operand QK^T keeps P entirely in registers.
// S = mfma(K,Q) -> lane owns one query (lane&31) x 16 key-rows; exp2+pack to
// bf16 pairs, 4 permlane32_swap per 32-key subtile repair the hi/lo key split,
// and the result feeds PV's A-fragment directly. No P LDS round-trip (the old
// 32 scalar ds_write_b16 + 4 ds_read_b128 per block are gone), no ones-MFMA
// row-sum (per-lane scalar l + 1 shfl_xor + 16 epilogue shfls instead).
// S-chain split into 2 accumulators to halve the dependent-MFMA depth.
// LDS = 64 KB (kt+vtile double-buffered) -> still 2 wgs/CU.
// ---------------------------------------------------------------------------
__global__ __launch_bounds__(256, 2) void attn_mfma(
    const ushort* __restrict__ q, const ushort* __restrict__ k,
    const ushort* __restrict__ vt, ushort* __restrict__ ctx) {
  const int tid = threadIdx.x;
  const int wave = tid >> 6;
  const int lane = tid & 63;
  const int m5 = lane & 31;
  const int hi = lane >> 5;

  int i = blockIdx.x;
  int bh, qt;
  if (i < 256) { bh = i >> 5; qt = 63 - (i & 31); }  // long jobs first
  else { i -= 256; bh = i >> 5; qt = i & 31; }       // complementary short
  const int hkv = bh & 3;
  const int b   = bh >> 2;
  const int h   = hkv * 4 + wave;
  const int q0  = qt * 32;

  __shared__ __align__(16) ushort kt[2][64 * 128];     // rows=key, 16 chunks ^15
  __shared__ __align__(16) ushort vtile[2][128 * 64];  // rows=d,   8 chunks ^7

  // Q frags (B-operand now): n=lane&31 (query), k = chunk*16 + hi*8 + j
  const ushort* qrow =
      q + ((size_t)(b * T_ + q0 + m5) * QH_ + h) * HD_ + hi * 8;
  bf16x8 qf[8];
#pragma unroll
  for (int c = 0; c < 8; ++c)
    qf[c] = *reinterpret_cast<const bf16x8*>(qrow + c * 16);

  f32x16 o4[4];
#pragma unroll
  for (int dt = 0; dt < 4; ++dt)
#pragma unroll
    for (int r = 0; r < 16; ++r) o4[dt][r] = 0.f;
  float ls = 0.f;  // per-lane partial row-sum (query m5, this hi's keys)

  const ushort* kbase = k + ((size_t)b * T_ * KVH_ + hkv) * HD_;
  const ushort* vbase = vt + (size_t)(b * KVD_ + hkv * HD_) * T_;

  const int nblk = (q0 + 32 + 63) >> 6;

  // ---- prologue: stage K,V block 0 ----
#pragma unroll
  for (int p = 0; p < 4; ++p) {
    const int c = p * 256 + tid;
    const int krow = c >> 4;
    const int kco = (c & 15) ^ (krow & 15);
    GLOAD_LDS16(kbase + (size_t)krow * KVD_ + kco * 8,
                kt[0] + (size_t)(p * 256 + wave * 64) * 8);
    const int vrow = c >> 3;
    const int vco = (c & 7) ^ (vrow & 7);
    GLOAD_LDS16(vbase + (size_t)vrow * T_ + vco * 8,
                vtile[0] + (size_t)(p * 256 + wave * 64) * 8);
  }
  __syncthreads();

  for (int blk = 0; blk < nblk; ++blk) {
    const int cur = blk & 1;
    const int j0 = blk * 64;

    if (blk + 1 < nblk) {
      const int j1 = j0 + 64;
#pragma unroll
      for (int p = 0; p < 4; ++p) {
        const int c = p * 256 + tid;
        const int krow = c >> 4;
        const int kco = (c & 15) ^ (krow & 15);
        GLOAD_LDS16(kbase + (size_t)(j1 + krow) * KVD_ + kco * 8,
                    kt[cur ^ 1] + (size_t)(p * 256 + wave * 64) * 8);
        const int vrow = c >> 3;
        const int vco = (c & 7) ^ (vrow & 7);
        GLOAD_LDS16(vbase + (size_t)vrow * T_ + j1 + vco * 8,
                    vtile[cur ^ 1] + (size_t)(p * 256 + wave * 64) * 8);
      }
    }

    const ushort* pk_ = kt[cur];
    const ushort* pv = vtile[cur];

    // ---- two 32-key sub-tiles ----
#pragma unroll
    for (int t2 = 0; t2 < 2; ++t2) {
      // S^T = K Q^T : A=K (m=key), B=Q (n=query). C: col=query, row=key.
      f32x16 sa0, sa1;
#pragma unroll
      for (int r = 0; r < 16; ++r) { sa0[r] = 0.f; sa1[r] = 0.f; }
      const int rowk = t2 * 32 + m5;  // key row in kt (A-frag: m=lane&31)
#pragma unroll
      for (int c = 0; c < 8; c += 2) {
        const int ch0 = (2 * c + hi) ^ (rowk & 15);
        bf16x8 kf0 =
            *reinterpret_cast<const bf16x8*>(pk_ + rowk * 128 + ch0 * 8);
        sa0 = __builtin_amdgcn_mfma_f32_32x32x16_bf16(kf0, qf[c], sa0, 0, 0, 0);
        const int ch1 = (2 * (c + 1) + hi) ^ (rowk & 15);
        bf16x8 kf1 =
            *reinterpret_cast<const bf16x8*>(pk_ + rowk * 128 + ch1 * 8);
        sa1 = __builtin_amdgcn_mfma_f32_32x32x16_bf16(kf1, qf[c + 1], sa1,
                                                      0, 0, 0);
      }
      f32x16 sa = sa0 + sa1;

      // lane holds P[key = t2*32 + (r&3)+8*(r>>2)+4*hi][query = m5]
      float p[16];
      if (blk == nblk - 1) {
#pragma unroll
        for (int r = 0; r < 16; ++r) {
          const int key = j0 + t2 * 32 + (r & 3) + 8 * (r >> 2) + 4 * hi;
          p[r] = (key > q0 + m5) ? 0.f : exp2f(sa[r]);
        }
      } else {
#pragma unroll
        for (int r = 0; r < 16; ++r) p[r] = exp2f(sa[r]);
      }
#pragma unroll
      for (int r = 0; r < 16; ++r) ls += p[r];

      // pack pairs: u0..u3 cover keys t2*32+0..15 (split by hi),
      // u4..u7 cover keys t2*32+16..31
      unsigned u0 = pk2(p[0], p[1]),   u1 = pk2(p[2], p[3]);
      unsigned u2 = pk2(p[4], p[5]),   u3 = pk2(p[6], p[7]);
      unsigned u4 = pk2(p[8], p[9]),   u5 = pk2(p[10], p[11]);
      unsigned u6 = pk2(p[12], p[13]), u7 = pk2(p[14], p[15]);
      // repair hi/lo key interleave -> A-frag order (k = hi*8 + j)
      hswap(u0, u2, hi); hswap(u1, u3, hi);
      hswap(u4, u6, hi); hswap(u5, u7, hi);

#pragma unroll
      for (int half = 0; half < 2; ++half) {
        union { unsigned w[4]; bf16x8 v; } pa;
        pa.w[0] = half ? u4 : u0;
        pa.w[1] = half ? u5 : u1;
        pa.w[2] = half ? u6 : u2;
        pa.w[3] = half ? u7 : u3;
        const int c = t2 * 2 + half;  // 16-key chunk within 64-block
#pragma unroll
        for (int dt = 0; dt < 4; ++dt) {
          const int rowv = dt * 32 + m5;  // d row in vtile (B-frag: n=lane&31)
          const int chv = (2 * c + hi) ^ (rowv & 7);
          bf16x8 vf =
              *reinterpret_cast<const bf16x8*>(pv + rowv * 64 + chv * 8);
          o4[dt] =
              __builtin_amdgcn_mfma_f32_32x32x16_bf16(pa.v, vf, o4[dt], 0, 0, 0);
        }
      }
    }

    __syncthreads();  // waves done with buf cur; prefetch into cur^1 drained
  }

  // ---- epilogue: O / l -> ctx bf16 [BT, QH*HD] ----
  const float lt = ls + __shfl_xor(ls, 32, 64);  // full row-sum for query m5
#pragma unroll
  for (int reg = 0; reg < 16; ++reg) {
    const int qrw = (reg & 3) + 8 * (reg >> 2) + 4 * hi;
    const float rl = 1.f / __shfl(lt, qrw, 64);
    ushort* op =
        ctx + ((size_t)(b * T_ + q0 + qrw) * QH_ + h) * HD_ + m5;
#pragma unroll
    for (int dt = 0; dt < 4; ++dt) {
      __hip_bfloat16 hb = __float2bfloat16(o4[dt][reg] * rl);
      op[dt * 32] = *(ushort*)&hb;
    }
  }
}

// ---------------------------------------------------------------------------
extern "C" void kernel_launch(void* const* d_in, const int* in_sizes, int n_in,
                              void* d_out, int out_size, void* d_ws, size_t ws_size,
                              hipStream_t stream) {
  const float* x  = (const float*)d_in[0];
  const int* pos  = (const int*)d_in[1];
  const float* wq = (const float*)d_in[2];
  const float* wk = (const float*)d_in[3];
  const float* wv = (const float*)d_in[4];
  const float* wo = (const float*)d_in[5];

  // Workspace (bf16 elements), 60 MB. Order must match cvt_all's segments.
  ushort* xb  = (ushort*)d_ws;              // 8388608 (reused as ctx)
  ushort* wqb = xb  + (size_t)8388608;      // 4194304
  ushort* wkb = wqb + (size_t)4194304;      // 1048576
  ushort* wvb = wkb + (size_t)1048576;      // 1048576
  ushort* wob = wvb + (size_t)1048576;      // 4194304
  ushort* qb  = wob + (size_t)4194304;      // 8388608
  ushort* kb  = qb  + (size_t)8388608;      // 2097152
  ushort* vtb = kb  + (size_t)2097152;      // 2097152
  ushort* ctx = xb;  // xb dead after gemm_qkv

  // fused fp32->bf16 conversions (wq pre-scaled by SCL)
  cvt_all<<<18432, 256, 0, stream>>>(x, wq, wk, wv, wo, (ushort*)d_ws);

  // fused QKV projection; V written pre-transposed (VT)
  gemm_qkv<<<(BT_ / 128) * 24, 256, 0, stream>>>(xb, wqb, wkb, wvb, qb, kb, vtb);

  // RoPE on q and k (in place)
  rope_kernel<<<(BT_ * (QH_ + KVH_)) / 4, 256, 0, stream>>>(
      (__hip_bfloat16*)qb, (__hip_bfloat16*)kb, pos);

  // flash MFMA attention -> ctx (512 wgs, complementary-qt pairing)
  attn_mfma<<<512, 256, 0, stream>>>(qb, kb, vtb, ctx);

  // output projection -> fp32 d_out
  gemm_o<<<(BT_ / 128) * (D_ / 128), 256, 0, stream>>>(
      ctx, wob, (float*)d_out, BT_, D_, QH_ * HD_);
}

// Round 2
// 312.988 us; speedup vs baseline: 1.0535x; 1.0423x over previous
//
#include <hip/hip_runtime.h>
#include <hip/hip_bf16.h>

typedef __bf16 bf16x8 __attribute__((ext_vector_type(8)));
typedef float  f32x4  __attribute__((ext_vector_type(4)));
typedef float  f32x16 __attribute__((ext_vector_type(16)));
typedef unsigned int u32x2 __attribute__((ext_vector_type(2)));

#define B_   2
#define T_   2048
#define D_   2048
#define QH_  16
#define KVH_ 4
#define HD_  128
#define BT_  (B_ * T_)
#define KVD_ 512
#define SCL  0.12751744f   // log2(e)/sqrt(128); folded into wq during cvt

// async global->LDS, 16B/lane; LDS dest = wave-uniform base + lane*16
#define GLOAD_LDS16(g, l)                                        \
  __builtin_amdgcn_global_load_lds(                              \
      (const __attribute__((address_space(1))) void*)(g),        \
      (__attribute__((address_space(3))) void*)(l), 16, 0, 0)

// ---------------------------------------------------------------------------
// Fused fp32->bf16 conversion for all five inputs -> [xb|wqb|wkb|wvb|wob].
// wq pre-scaled by SCL so QK^T scores come out in exp2 domain.
// ---------------------------------------------------------------------------
__global__ __launch_bounds__(256) void cvt_all(
    const float* __restrict__ x, const float* __restrict__ wq,
    const float* __restrict__ wk, const float* __restrict__ wv,
    const float* __restrict__ wo, ushort* __restrict__ out) {
  const int i = blockIdx.x * 256 + threadIdx.x;  // float4 idx; 4718592 total
  int j = i;
  const float* src;
  float mul = 1.f;
  if (j < 2097152) { src = x; }
  else if ((j -= 2097152) < 1048576) { src = wq; mul = SCL; }
  else if ((j -= 1048576) < 262144)  { src = wk; }
  else if ((j -= 262144) < 262144)   { src = wv; }
  else { j -= 262144; src = wo; }
  float4 v = ((const float4*)src)[j];
  __hip_bfloat16 h0 = __float2bfloat16(v.x * mul);
  __hip_bfloat16 h1 = __float2bfloat16(v.y * mul);
  __hip_bfloat16 h2 = __float2bfloat16(v.z * mul);
  __hip_bfloat16 h3 = __float2bfloat16(v.w * mul);
  ushort4 o;
  o.x = *(ushort*)&h0; o.y = *(ushort*)&h1;
  o.z = *(ushort*)&h2; o.w = *(ushort*)&h3;
  ((ushort4*)out)[i] = o;
}

// ---------------------------------------------------------------------------
// Fused QKV projection, 128x128 tile, BK=64, XOR-swizzled LDS chunks.
// v2: 2-deep double-buffered pipeline with counted vmcnt (T3/T4): loads for
// K-tile t+2 stay in flight across the barriers while tile t computes; raw
// s_barrier + manual s_waitcnt so the compiler can't drain vmcnt to 0.
// ---------------------------------------------------------------------------
__global__ __launch_bounds__(256) void gemm_qkv(
    const ushort* __restrict__ X, const ushort* __restrict__ WQ,
    const ushort* __restrict__ WK, const ushort* __restrict__ WV,
    ushort* __restrict__ qo, ushort* __restrict__ ko, ushort* __restrict__ vo) {
  const int nb = blockIdx.x % 24;
  const int mb = blockIdx.x / 24;
  const int tid = threadIdx.x;
  const int wave = tid >> 6;
  const int lane = tid & 63;
  const int mrow = lane & 15;
  const int quad = lane >> 4;
  const int wm = wave >> 1;
  const int wn = wave & 1;
  const int m0 = mb * 128;
  const int K = D_;

  const ushort* Wg;
  if (nb < 16)      Wg = WQ + (size_t)nb * 128 * K;
  else if (nb < 20) Wg = WK + (size_t)(nb - 16) * 128 * K;
  else              Wg = WV + (size_t)(nb - 20) * 128 * K;

  __shared__ __align__(16) ushort At[2][128 * 64];  // 32 KB dbuf
  __shared__ __align__(16) ushort Bt[2][128 * 64];  // 32 KB dbuf

  f32x4 acc[4][4];
#pragma unroll
  for (int i = 0; i < 4; ++i)
#pragma unroll
    for (int j = 0; j < 4; ++j) acc[i][j] = (f32x4){0.f, 0.f, 0.f, 0.f};

  const ushort* Xg = X + (size_t)m0 * K;

  auto STAGE = [&](int buf, int k0) {
#pragma unroll
    for (int p = 0; p < 4; ++p) {
      const int c = p * 256 + tid;
      const int row = c >> 3;
      const int cc = (c & 7) ^ (row & 7);
      GLOAD_LDS16(Xg + (size_t)row * K + k0 + cc * 8,
                  At[buf] + (size_t)(p * 256 + wave * 64) * 8);
      GLOAD_LDS16(Wg + (size_t)row * K + k0 + cc * 8,
                  Bt[buf] + (size_t)(p * 256 + wave * 64) * 8);
    }
  };

  const int NT = K / 64;  // 32
  STAGE(0, 0);
  STAGE(1, 64);

  for (int t = 0; t < NT; ++t) {
    const int cur = t & 1;
    // wait for buf[cur]'s 8 loads (8 newer ones for buf[cur^1] stay in flight)
    if (t + 2 < NT) asm volatile("s_waitcnt vmcnt(8)" ::: "memory");
    else            asm volatile("s_waitcnt vmcnt(0)" ::: "memory");
    __builtin_amdgcn_s_barrier();

    const ushort* Ac = At[cur];
    const ushort* Bc = Bt[cur];
#pragma unroll
    for (int s = 0; s < 2; ++s) {
      bf16x8 af[4], bfr[4];
#pragma unroll
      for (int mt = 0; mt < 4; ++mt) {
        const int row = wm * 64 + mt * 16 + mrow;
        af[mt] = *reinterpret_cast<const bf16x8*>(
            Ac + row * 64 + (((s * 4 + quad) ^ (row & 7)) * 8));
      }
#pragma unroll
      for (int nt = 0; nt < 4; ++nt) {
        const int row = wn * 64 + nt * 16 + mrow;
        bfr[nt] = *reinterpret_cast<const bf16x8*>(
            Bc + row * 64 + (((s * 4 + quad) ^ (row & 7)) * 8));
      }
#pragma unroll
      for (int mt = 0; mt < 4; ++mt)
#pragma unroll
        for (int nt = 0; nt < 4; ++nt)
          acc[mt][nt] = __builtin_amdgcn_mfma_f32_16x16x32_bf16(
              af[mt], bfr[nt], acc[mt][nt], 0, 0, 0);
    }

    asm volatile("s_waitcnt lgkmcnt(0)" ::: "memory");
    __builtin_amdgcn_s_barrier();  // all waves done reading buf[cur]
    if (t + 2 < NT) STAGE(cur, (t + 2) * 64);
  }

#pragma unroll
  for (int mt = 0; mt < 4; ++mt) {
#pragma unroll
    for (int nt = 0; nt < 4; ++nt) {
      const int colw = wn * 64 + nt * 16 + mrow;
      const int row0 = m0 + wm * 64 + mt * 16 + quad * 4;
      if (nb < 16) {
        const int col = nb * 128 + colw;
#pragma unroll
        for (int r = 0; r < 4; ++r) {
          __hip_bfloat16 hh = __float2bfloat16(acc[mt][nt][r]);
          qo[(size_t)(row0 + r) * 2048 + col] = *(ushort*)&hh;
        }
      } else if (nb < 20) {
        const int col = (nb - 16) * 128 + colw;
#pragma unroll
        for (int r = 0; r < 4; ++r) {
          __hip_bfloat16 hh = __float2bfloat16(acc[mt][nt][r]);
          ko[(size_t)(row0 + r) * KVD_ + col] = *(ushort*)&hh;
        }
      } else {
        const int col = (nb - 20) * 128 + colw;
        const int bb = row0 >> 11;
        const int t0 = row0 & (T_ - 1);
        ushort4 s4;
#pragma unroll
        for (int r = 0; r < 4; ++r) {
          __hip_bfloat16 hh = __float2bfloat16(acc[mt][nt][r]);
          (&s4.x)[r] = *(ushort*)&hh;
        }
        *(ushort4*)(vo + ((size_t)(bb * KVD_ + col)) * T_ + t0) = s4;
      }
    }
  }
}

// ---------------------------------------------------------------------------
// O-projection GEMM (fp32 out), same 2-deep counted-vmcnt pipeline.
// ---------------------------------------------------------------------------
__global__ __launch_bounds__(256) void gemm_o(
    const ushort* __restrict__ X, const ushort* __restrict__ W,
    float* __restrict__ Y, int M, int N, int K) {
  const int nb128 = N >> 7;
  const int mb = blockIdx.x / nb128;
  const int nb = blockIdx.x % nb128;
  const int tid = threadIdx.x;
  const int wave = tid >> 6;
  const int lane = tid & 63;
  const int mrow = lane & 15;
  const int quad = lane >> 4;
  const int wm = wave >> 1;
  const int wn = wave & 1;
  const int m0 = mb * 128;
  const int n0 = nb * 128;

  __shared__ __align__(16) ushort At[2][128 * 64];
  __shared__ __align__(16) ushort Bt[2][128 * 64];

  f32x4 acc[4][4];
#pragma unroll
  for (int i = 0; i < 4; ++i)
#pragma unroll
    for (int j = 0; j < 4; ++j) acc[i][j] = (f32x4){0.f, 0.f, 0.f, 0.f};

  const ushort* Xg = X + (size_t)m0 * K;
  const ushort* Wg = W + (size_t)n0 * K;

  auto STAGE = [&](int buf, int k0) {
#pragma unroll
    for (int p = 0; p < 4; ++p) {
      const int c = p * 256 + tid;
      const int row = c >> 3;
      const int cc = (c & 7) ^ (row & 7);
      GLOAD_LDS16(Xg + (size_t)row * K + k0 + cc * 8,
                  At[buf] + (size_t)(p * 256 + wave * 64) * 8);
      GLOAD_LDS16(Wg + (size_t)row * K + k0 + cc * 8,
                  Bt[buf] + (size_t)(p * 256 + wave * 64) * 8);
    }
  };

  const int NT = K / 64;
  STAGE(0, 0);
  STAGE(1, 64);

  for (int t = 0; t < NT; ++t) {
    const int cur = t & 1;
    if (t + 2 < NT) asm volatile("s_waitcnt vmcnt(8)" ::: "memory");
    else            asm volatile("s_waitcnt vmcnt(0)" ::: "memory");
    __builtin_amdgcn_s_barrier();

    const ushort* Ac = At[cur];
    const ushort* Bc = Bt[cur];
#pragma unroll
    for (int s = 0; s < 2; ++s) {
      bf16x8 af[4], bfr[4];
#pragma unroll
      for (int mt = 0; mt < 4; ++mt) {
        const int row = wm * 64 + mt * 16 + mrow;
        af[mt] = *reinterpret_cast<const bf16x8*>(
            Ac + row * 64 + (((s * 4 + quad) ^ (row & 7)) * 8));
      }
#pragma unroll
      for (int nt = 0; nt < 4; ++nt) {
        const int row = wn * 64 + nt * 16 + mrow;
        bfr[nt] = *reinterpret_cast<const bf16x8*>(
            Bc + row * 64 + (((s * 4 + quad) ^ (row & 7)) * 8));
      }
#pragma unroll
      for (int mt = 0; mt < 4; ++mt)
#pragma unroll
        for (int nt = 0; nt < 4; ++nt)
          acc[mt][nt] = __builtin_amdgcn_mfma_f32_16x16x32_bf16(
              af[mt], bfr[nt], acc[mt][nt], 0, 0, 0);
    }

    asm volatile("s_waitcnt lgkmcnt(0)" ::: "memory");
    __builtin_amdgcn_s_barrier();
    if (t + 2 < NT) STAGE(cur, (t + 2) * 64);
  }

#pragma unroll
  for (int mt = 0; mt < 4; ++mt)
#pragma unroll
    for (int nt = 0; nt < 4; ++nt) {
      const int col = n0 + wn * 64 + nt * 16 + mrow;
      const int row0 = m0 + wm * 64 + mt * 16 + quad * 4;
#pragma unroll
      for (int r = 0; r < 4; ++r)
        Y[(size_t)(row0 + r) * N + col] = acc[mt][nt][r];
    }
}

// ---------------------------------------------------------------------------
// RoPE in place on bf16 q [BT,16,128] (pre-scaled; rotation commutes) and k.
// ---------------------------------------------------------------------------
__global__ __launch_bounds__(256) void rope_kernel(
    __hip_bfloat16* __restrict__ q, __hip_bfloat16* __restrict__ k,
    const int* __restrict__ positions) {
  const int wave = threadIdx.x >> 6;
  const int lane = threadIdx.x & 63;
  const int p = blockIdx.x * 4 + wave;
  const int head = p % (QH_ + KVH_);
  const int bt = p / (QH_ + KVH_);

  __hip_bfloat16* base;
  if (head < QH_) base = q + ((size_t)bt * QH_ + head) * HD_;
  else            base = k + ((size_t)bt * KVH_ + (head - QH_)) * HD_;

  const float pos = (float)positions[bt];
  const float inv_freq = exp2f((float)lane * -0.20762050593f);  // -log2(1e4)/64
  const float ang = pos * inv_freq;
  const float c = cosf(ang);
  const float s = sinf(ang);

  const float x1 = __bfloat162float(base[lane]);
  const float x2 = __bfloat162float(base[lane + 64]);
  base[lane]      = __float2bfloat16(x1 * c - x2 * s);
  base[lane + 64] = __float2bfloat16(x1 * s + x2 * c);
}

// ---------------------------------------------------------------------------
// pack 2 f32 -> 1 u32 of 2 bf16 (compiler fuses to v_cvt_pk_bf16_f32)
// ---------------------------------------------------------------------------
static __device__ __forceinline__ unsigned pk2(float a, float b) {
  __hip_bfloat16 ha = __float2bfloat16(a);
  __hip_bfloat16 hb = __float2bfloat16(b);
  return (unsigned)(*(ushort*)&ha) | ((unsigned)(*(ushort*)&hb) << 16);
}

// exchange upper-32-lanes of a with lower-32-lanes of b
static __device__ __forceinline__ void hswap(unsigned& a, unsigned& b,
                                             const int hi) {
#if __has_builtin(__builtin_amdgcn_permlane32_swap)
  u32x2 r = __builtin_amdgcn_permlane32_swap(a, b, false, false);
  a = r.x;
  b = r.y;
#else
  unsigned s = __shfl_xor(hi ? a : b, 32, 64);
  unsigned na = hi ? s : a;
  b = hi ? b : s;
  a = na;
#endif
}

// ---------------------------------------------------------------------------
// Flash MFMA attention v5: swapped-operand QK^T keeps P entirely in registers.
// ---------------------------------------------------------------------------
__global__ __launch_bounds__(256, 2) void attn_mfma(
    const ushort* __restrict__ q, const ushort* __restrict__ k,
    const ushort* __restrict__ vt, ushort* __restrict__ ctx) {
  const int tid = threadIdx.x;
  const int wave = tid >> 6;
  const int lane = tid & 63;
  const int m5 = lane & 31;
  const int hi = lane >> 5;

  int i = blockIdx.x;
  int bh, qt;
  if (i < 256) { bh = i >> 5; qt = 63 - (i & 31); }  // long jobs first
  else { i -= 256; bh = i >> 5; qt = i & 31; }       // complementary short
  const int hkv = bh & 3;
  const int b   = bh >> 2;
  const int h   = hkv * 4 + wave;
  const int q0  = qt * 32;

  __shared__ __align__(16) ushort kt[2][64 * 128];     // rows=key, 16 chunks ^15
  __shared__ __align__(16) ushort vtile[2][128 * 64];  // rows=d,   8 chunks ^7

  // Q frags (B-operand now): n=lane&31 (query), k = chunk*16 + hi*8 + j
  const ushort* qrow =
      q + ((size_t)(b * T_ + q0 + m5) * QH_ + h) * HD_ + hi * 8;
  bf16x8 qf[8];
#pragma unroll
  for (int c = 0; c < 8; ++c)
    qf[c] = *reinterpret_cast<const bf16x8*>(qrow + c * 16);

  f32x16 o4[4];
#pragma unroll
  for (int dt = 0; dt < 4; ++dt)
#pragma unroll
    for (int r = 0; r < 16; ++r) o4[dt][r] = 0.f;
  float ls = 0.f;  // per-lane partial row-sum (query m5, this hi's keys)

  const ushort* kbase = k + ((size_t)b * T_ * KVH_ + hkv) * HD_;
  const ushort* vbase = vt + (size_t)(b * KVD_ + hkv * HD_) * T_;

  const int nblk = (q0 + 32 + 63) >> 6;

  // ---- prologue: stage K,V block 0 ----
#pragma unroll
  for (int p = 0; p < 4; ++p) {
    const int c = p * 256 + tid;
    const int krow = c >> 4;
    const int kco = (c & 15) ^ (krow & 15);
    GLOAD_LDS16(kbase + (size_t)krow * KVD_ + kco * 8,
                kt[0] + (size_t)(p * 256 + wave * 64) * 8);
    const int vrow = c >> 3;
    const int vco = (c & 7) ^ (vrow & 7);
    GLOAD_LDS16(vbase + (size_t)vrow * T_ + vco * 8,
                vtile[0] + (size_t)(p * 256 + wave * 64) * 8);
  }
  __syncthreads();

  for (int blk = 0; blk < nblk; ++blk) {
    const int cur = blk & 1;
    const int j0 = blk * 64;

    if (blk + 1 < nblk) {
      const int j1 = j0 + 64;
#pragma unroll
      for (int p = 0; p < 4; ++p) {
        const int c = p * 256 + tid;
        const int krow = c >> 4;
        const int kco = (c & 15) ^ (krow & 15);
        GLOAD_LDS16(kbase + (size_t)(j1 + krow) * KVD_ + kco * 8,
                    kt[cur ^ 1] + (size_t)(p * 256 + wave * 64) * 8);
        const int vrow = c >> 3;
        const int vco = (c & 7) ^ (vrow & 7);
        GLOAD_LDS16(vbase + (size_t)vrow * T_ + j1 + vco * 8,
                    vtile[cur ^ 1] + (size_t)(p * 256 + wave * 64) * 8);
      }
    }

    const ushort* pk_ = kt[cur];
    const ushort* pv = vtile[cur];

    // ---- two 32-key sub-tiles ----
#pragma unroll
    for (int t2 = 0; t2 < 2; ++t2) {
      // S^T = K Q^T : A=K (m=key), B=Q (n=query). C: col=query, row=key.
      f32x16 sa0, sa1;
#pragma unroll
      for (int r = 0; r < 16; ++r) { sa0[r] = 0.f; sa1[r] = 0.f; }
      const int rowk = t2 * 32 + m5;  // key row in kt (A-frag: m=lane&31)
#pragma unroll
      for (int c = 0; c < 8; c += 2) {
        const int ch0 = (2 * c + hi) ^ (rowk & 15);
        bf16x8 kf0 =
            *reinterpret_cast<const bf16x8*>(pk_ + rowk * 128 + ch0 * 8);
        sa0 = __builtin_amdgcn_mfma_f32_32x32x16_bf16(kf0, qf[c], sa0, 0, 0, 0);
        const int ch1 = (2 * (c + 1) + hi) ^ (rowk & 15);
        bf16x8 kf1 =
            *reinterpret_cast<const bf16x8*>(pk_ + rowk * 128 + ch1 * 8);
        sa1 = __builtin_amdgcn_mfma_f32_32x32x16_bf16(kf1, qf[c + 1], sa1,
                                                      0, 0, 0);
      }
      f32x16 sa = sa0 + sa1;

      // lane holds P[key = t2*32 + (r&3)+8*(r>>2)+4*hi][query = m5]
      float p[16];
      if (blk == nblk - 1) {
#pragma unroll
        for (int r = 0; r < 16; ++r) {
          const int key = j0 + t2 * 32 + (r & 3) + 8 * (r >> 2) + 4 * hi;
          p[r] = (key > q0 + m5) ? 0.f : exp2f(sa[r]);
        }
      } else {
#pragma unroll
        for (int r = 0; r < 16; ++r) p[r] = exp2f(sa[r]);
      }
#pragma unroll
      for (int r = 0; r < 16; ++r) ls += p[r];

      // pack pairs: u0..u3 cover keys t2*32+0..15 (split by hi),
      // u4..u7 cover keys t2*32+16..31
      unsigned u0 = pk2(p[0], p[1]),   u1 = pk2(p[2], p[3]);
      unsigned u2 = pk2(p[4], p[5]),   u3 = pk2(p[6], p[7]);
      unsigned u4 = pk2(p[8], p[9]),   u5 = pk2(p[10], p[11]);
      unsigned u6 = pk2(p[12], p[13]), u7 = pk2(p[14], p[15]);
      // repair hi/lo key interleave -> A-frag order (k = hi*8 + j)
      hswap(u0, u2, hi); hswap(u1, u3, hi);
      hswap(u4, u6, hi); hswap(u5, u7, hi);

#pragma unroll
      for (int half = 0; half < 2; ++half) {
        union { unsigned w[4]; bf16x8 v; } pa;
        pa.w[0] = half ? u4 : u0;
        pa.w[1] = half ? u5 : u1;
        pa.w[2] = half ? u6 : u2;
        pa.w[3] = half ? u7 : u3;
        const int c = t2 * 2 + half;  // 16-key chunk within 64-block
#pragma unroll
        for (int dt = 0; dt < 4; ++dt) {
          const int rowv = dt * 32 + m5;  // d row in vtile (B-frag: n=lane&31)
          const int chv = (2 * c + hi) ^ (rowv & 7);
          bf16x8 vf =
              *reinterpret_cast<const bf16x8*>(pv + rowv * 64 + chv * 8);
          o4[dt] =
              __builtin_amdgcn_mfma_f32_32x32x16_bf16(pa.v, vf, o4[dt], 0, 0, 0);
        }
      }
    }

    __syncthreads();  // waves done with buf cur; prefetch into cur^1 drained
  }

  // ---- epilogue: O / l -> ctx bf16 [BT, QH*HD] ----
  const float lt = ls + __shfl_xor(ls, 32, 64);  // full row-sum for query m5
#pragma unroll
  for (int reg = 0; reg < 16; ++reg) {
    const int qrw = (reg & 3) + 8 * (reg >> 2) + 4 * hi;
    const float rl = 1.f / __shfl(lt, qrw, 64);
    ushort* op =
        ctx + ((size_t)(b * T_ + q0 + qrw) * QH_ + h) * HD_ + m5;
#pragma unroll
    for (int dt = 0; dt < 4; ++dt) {
      __hip_bfloat16 hb = __float2bfloat16(o4[dt][reg] * rl);
      op[dt * 32] = *(ushort*)&hb;
    }
  }
}

// ---------------------------------------------------------------------------
extern "C" void kernel_launch(void* const* d_in, const int* in_sizes, int n_in,
                              void* d_out, int out_size, void* d_ws, size_t ws_size,
                              hipStream_t stream) {
  const float* x  = (const float*)d_in[0];
  const int* pos  = (const int*)d_in[1];
  const float* wq = (const float*)d_in[2];
  const float* wk = (const float*)d_in[3];
  const float* wv = (const float*)d_in[4];
  const float* wo = (const float*)d_in[5];

  // Workspace (bf16 elements), 60 MB. Order must match cvt_all's segments.
  ushort* xb  = (ushort*)d_ws;              // 8388608 (reused as ctx)
  ushort* wqb = xb  + (size_t)8388608;      // 4194304
  ushort* wkb = wqb + (size_t)4194304;      // 1048576
  ushort* wvb = wkb + (size_t)1048576;      // 1048576
  ushort* wob = wvb + (size_t)1048576;      // 4194304
  ushort* qb  = wob + (size_t)4194304;      // 8388608
  ushort* kb  = qb  + (size_t)8388608;      // 2097152
  ushort* vtb = kb  + (size_t)2097152;      // 2097152
  ushort* ctx = xb;  // xb dead after gemm_qkv

  // fused fp32->bf16 conversions (wq pre-scaled by SCL)
  cvt_all<<<18432, 256, 0, stream>>>(x, wq, wk, wv, wo, (ushort*)d_ws);

  // fused QKV projection; V written pre-transposed (VT)
  gemm_qkv<<<(BT_ / 128) * 24, 256, 0, stream>>>(xb, wqb, wkb, wvb, qb, kb, vtb);

  // RoPE on q and k (in place)
  rope_kernel<<<(BT_ * (QH_ + KVH_)) / 4, 256, 0, stream>>>(
      (__hip_bfloat16*)qb, (__hip_bfloat16*)kb, pos);

  // flash MFMA attention -> ctx (512 wgs, complementary-qt pairing)
  attn_mfma<<<512, 256, 0, stream>>>(qb, kb, vtb, ctx);

  // output projection -> fp32 d_out
  gemm_o<<<(BT_ / 128) * (D_ / 128), 256, 0, stream>>>(
      ctx, wob, (float*)d_out, BT_, D_, QH_ * HD_);
}